// Round 1
// 89.905 us; speedup vs baseline: 1.0030x; 1.0030x over previous
//
#include <hip/hip_runtime.h>

#define N_PTS 65536
#define BATCH 8
#define KCL   64
#define CHUNK 1024
#define LOG2E 1.44269504088896340736f

typedef float f32x2 __attribute__((ext_vector_type(2)));
typedef float f32x4 __attribute__((ext_vector_type(4)));

// fp64 reciprocal: float rcp seed + 2 Newton iterations (quadratic: ~1e-7 -> 1e-14 -> <eps)
__device__ __forceinline__ double drcp(double x) {
    double r = (double)(1.0f / (float)x);
    r = r * (2.0 - x * r);
    r = r * (2.0 - x * r);
    return r;
}

__device__ __forceinline__ float hw_exp2(float x) {
    return __builtin_amdgcn_exp2f(x);
}

// K1: no atomics (round-12/13 confirmed the atomic tail was the ~25 us invariant).
// Each block stores its 64x float4 partials to a private coalesced slice.
// part float4 idx: (sb*64+chunk)*64 + k.
__global__ __launch_bounds__(256) void k_sum(const float* __restrict__ tmpl,
                                             const float* __restrict__ srcf,
                                             const float* __restrict__ Wmat,
                                             float* __restrict__ part) {
    const int bx    = blockIdx.x;       // 0..1023
    const int set   = bx >> 9;          // 512 blocks per set
    const int b     = (bx >> 6) & 7;    // 64 blocks per (set,b)
    const int chunk = bx & 63;          // 1024-point chunk
    const float* feat = set ? srcf : tmpl;
    const int n0 = chunk * CHUNK;

    __shared__ float xs[3][CHUNK];
    __shared__ float red[4][KCL][8];

    const int tid  = threadIdx.x;
    const int lane = tid & 63;
    const int wv   = tid >> 6;

    // async global->LDS staging (round-7 proven in-bounds geometry):
    // wave wv, plane j: 64 lanes x 16 B = 256 floats at &xs[j][wv*256]
    const float* base = feat + (size_t)b * 3 * N_PTS + n0;
#pragma unroll
    for (int j = 0; j < 3; ++j) {
        const float* g = base + (size_t)j * N_PTS + wv * 256 + lane * 4;
        __builtin_amdgcn_global_load_lds(
            (const __attribute__((address_space(1))) void*)g,
            (__attribute__((address_space(3))) void*)&xs[j][wv * 256],
            16, 0, 0);
    }
    __syncthreads();

    // half h = lane>>5 (point group), cluster pair cA = lane&31:
    // lane handles clusters {cA, cA+32}; lanes l and l+32 hold the SAME pair.
    const int h  = lane >> 5;
    const int cA = lane & 31;
    const float w0a = Wmat[cA] * LOG2E,         w0b = Wmat[cA + 32] * LOG2E;
    const float w1a = Wmat[KCL + cA] * LOG2E,   w1b = Wmat[KCL + cA + 32] * LOG2E;
    const float w2a = Wmat[2*KCL + cA] * LOG2E, w2b = Wmat[2*KCL + cA + 32] * LOG2E;
    const f32x2 w0av = {w0a, w0a}, w1av = {w1a, w1a}, w2av = {w2a, w2a};
    const f32x2 w0bv = {w0b, w0b}, w1bv = {w1b, w1b}, w2bv = {w2b, w2b};

    f32x2 zA = {0,0}, s0A = {0,0}, s1A = {0,0}, s2A = {0,0};
    f32x2 zB = {0,0}, s0B = {0,0}, s1B = {0,0}, s2B = {0,0};

    const f32x4* lp0 = (const f32x4*)&xs[0][0];
    const f32x4* lp1 = (const f32x4*)&xs[1][0];
    const f32x4* lp2 = (const f32x4*)&xs[2][0];

#pragma unroll 2
    for (int it = 0; it < 32; ++it) {
        const int q = wv * 64 + it * 2 + h;   // two distinct addresses per wave
        f32x4 a = lp0[q];
        f32x4 c = lp1[q];
        f32x4 d = lp2[q];
#pragma unroll
        for (int p = 0; p < 2; ++p) {
            f32x2 ax = p ? a.zw : a.xy;
            f32x2 cx = p ? c.zw : c.xy;
            f32x2 dx = p ? d.zw : d.xy;
            {
                f32x2 l = __builtin_elementwise_fma(ax, w0av,
                            __builtin_elementwise_fma(cx, w1av, dx * w2av));
                f32x2 e = {hw_exp2(l.x), hw_exp2(l.y)};
                zA += e;
                s0A = __builtin_elementwise_fma(e, ax, s0A);
                s1A = __builtin_elementwise_fma(e, cx, s1A);
                s2A = __builtin_elementwise_fma(e, dx, s2A);
            }
            {
                f32x2 l = __builtin_elementwise_fma(ax, w0bv,
                            __builtin_elementwise_fma(cx, w1bv, dx * w2bv));
                f32x2 e = {hw_exp2(l.x), hw_exp2(l.y)};
                zB += e;
                s0B = __builtin_elementwise_fma(e, ax, s0B);
                s1B = __builtin_elementwise_fma(e, cx, s1B);
                s2B = __builtin_elementwise_fma(e, dx, s2B);
            }
        }
    }

    // vectorized epilogue: 2x ds_write_b128 per lane (was 8 scalar writes,
    // 16-way bank-conflicted); b128 internal 4-dword sweep is ~4-way, free-ish.
    f32x4 ra = {zA.x + zA.y, s0A.x + s0A.y, s1A.x + s1A.y, s2A.x + s2A.y};
    f32x4 rb = {zB.x + zB.y, s0B.x + s0B.y, s1B.x + s1B.y, s2B.x + s2B.y};
    *(f32x4*)&red[wv][lane][0] = ra;
    *(f32x4*)&red[wv][lane][4] = rb;
    __syncthreads();

    if (tid < KCL) {
        // cluster c: partials live in lanes {c&31, (c&31)+32}, slot (c>>5)*4
        const int cl = tid & 31;
        const int sb = (tid >> 5) * 4;
        float rz = 0, rs0 = 0, rs1 = 0, rs2 = 0;
#pragma unroll
        for (int w = 0; w < 4; ++w) {
            rz  += red[w][cl][sb + 0] + red[w][cl + 32][sb + 0];
            rs0 += red[w][cl][sb + 1] + red[w][cl + 32][sb + 1];
            rs1 += red[w][cl][sb + 2] + red[w][cl + 32][sb + 2];
            rs2 += red[w][cl][sb + 3] + red[w][cl + 32][sb + 3];
        }
        float4 v = {rz, rs0, rs1, rs2};
        ((float4*)part)[bx * 64 + tid] = v;   // private slice, coalesced, no atomics
    }
}

// K2: parallel partial reduction, 16 blocks (one per (set,b)); ~3 us
// (2 MB through 16 CUs). Coalesced: consecutive k per lane.
__global__ __launch_bounds__(256) void k_reduce(const float* __restrict__ part,
                                                float* __restrict__ Zs,
                                                float* __restrict__ Ss) {
    const int sb  = blockIdx.x;        // 0..15 = set*8+b
    const int tid = threadIdx.x;
    const int k   = tid & 63;
    const int qr  = tid >> 6;          // quarter 0..3

    const float4* p = (const float4*)part;
    const int base = sb * 4096 + qr * 16 * 64 + k;   // (sb*64 + qr*16 + ch)*64 + k
    float z = 0, s0 = 0, s1 = 0, s2 = 0;
#pragma unroll 4
    for (int ch = 0; ch < 16; ++ch) {
        float4 v = p[base + ch * 64];
        z += v.x; s0 += v.y; s1 += v.z; s2 += v.w;
    }

    __shared__ float red[4][64][4];
    red[qr][k][0] = z;
    red[qr][k][1] = s0;
    red[qr][k][2] = s1;
    red[qr][k][3] = s2;
    __syncthreads();
    if (tid < 64) {
        float rz  = red[0][tid][0] + red[1][tid][0] + red[2][tid][0] + red[3][tid][0];
        float rs0 = red[0][tid][1] + red[1][tid][1] + red[2][tid][1] + red[3][tid][1];
        float rs1 = red[0][tid][2] + red[1][tid][2] + red[2][tid][2] + red[3][tid][2];
        float rs2 = red[0][tid][3] + red[1][tid][3] + red[2][tid][3] + red[3][tid][3];
        const int idx = sb * 64 + tid;
        Zs[idx] = rz;
        Ss[idx * 3 + 0] = rs0;
        Ss[idx * 3 + 1] = rs1;
        Ss[idx * 3 + 2] = rs2;
    }
}

// K3 (fused solve+apply): LOAD-FIRST structure retained -- all 256 threads issue
// their source loads before the solve branch; uses are after __syncthreads, so
// the compiler's vmcnt wait lands post-solve and the fp64 solve latency overlaps
// the load stream. NEW this round: each thread owns 4 CONSECUTIVE points ->
// 3x float4 loads + 3x float4 stores (was 12 scalar loads + 12 stride-3 scalar
// stores). 4x fewer VMEM instructions, 16 B/lane fully-coalesced both ways.
__global__ __launch_bounds__(256) void k_apply(const float* __restrict__ srcf,
                                               const float* __restrict__ Zs,
                                               const float* __restrict__ Ss,
                                               float* __restrict__ out) {
    __shared__ float rt_s[BATCH][12];

    // ---- phase 0: issue all source loads (in flight during the solve) ----
    const int t    = blockIdx.x * 256 + threadIdx.x;   // 0..131071
    const int idx0 = t << 2;                           // first of 4 consecutive points
    const int b    = idx0 >> 16;                       // whole block is in one b (64 blk/b)
    const int n    = idx0 & (N_PTS - 1);
    const float* base = srcf + (size_t)b * 3 * N_PTS + n;
    f32x4 xa = *(const f32x4*)(base);                  // dim 0, points n..n+3
    f32x4 xb = *(const f32x4*)(base + N_PTS);          // dim 1
    f32x4 xc = *(const f32x4*)(base + 2 * N_PTS);      // dim 2

    // ---- phase 1: redundant per-block fp64 polar solve (threads 0-63) ----
    if (threadIdx.x < 64) {
        const int lane = threadIdx.x;
        const int bb   = lane >> 3;
        const int sub  = lane & 7;

        const double inv_npi = 1.0 / (1.0 + 2e-8);        // Npi = 1+eps, /(Npi+eps)
        const double pi_c = (1.0 + 1e-8) / (double)N_PTS; // pi[b,k] constant

        double Mt[3] = {0, 0, 0}, Ms[3] = {0, 0, 0};
        double P[3][3] = {{0,0,0},{0,0,0},{0,0,0}};
        for (int kk = 0; kk < 8; ++kk) {
            int k  = sub * 8 + kk;
            int it = bb * KCL + k;                 // set 0 (template)
            int is = (BATCH + bb) * KCL + k;       // set 1 (source)
            double izt = inv_npi * drcp((double)Zs[it]);
            double izs = inv_npi * drcp((double)Zs[is]);
            double mt[3], ms[3];
            for (int d = 0; d < 3; ++d) {
                mt[d] = (double)Ss[it * 3 + d] * izt;
                ms[d] = (double)Ss[is * 3 + d] * izs;
                Mt[d] += mt[d];
                Ms[d] += ms[d];
            }
            for (int d = 0; d < 3; ++d)
                for (int e = 0; e < 3; ++e)
                    P[d][e] += mt[d] * ms[e];
        }
        // butterfly reduce across the 8 sub-lanes (masks 1,2,4 stay in-group)
        for (int m = 1; m <= 4; m <<= 1) {
            for (int d = 0; d < 3; ++d) {
                Mt[d] += __shfl_xor(Mt[d], m, 64);
                Ms[d] += __shfl_xor(Ms[d], m, 64);
            }
            for (int d = 0; d < 3; ++d)
                for (int e = 0; e < 3; ++e)
                    P[d][e] += __shfl_xor(P[d][e], m, 64);
        }

        double cy[3], cx[3];
        for (int d = 0; d < 3; ++d) { cy[d] = pi_c * Mt[d]; cx[d] = pi_c * Ms[d]; }

        const double coef = 2.0 * pi_c - 64.0 * pi_c * pi_c;
        double A[3][3];
        for (int d = 0; d < 3; ++d)
            for (int e = 0; e < 3; ++e)
                A[d][e] = pi_c * (P[d][e] - coef * Mt[d] * Ms[e]);

        // G = A^T A
        double G[3][3];
        for (int i = 0; i < 3; ++i)
            for (int j = 0; j < 3; ++j) {
                double acc = 0;
                for (int d = 0; d < 3; ++d) acc += A[d][i] * A[d][j];
                G[i][j] = acc;
            }

        // Jacobi eigendecomposition of G (6 sweeps; tolerance exit fires ~5)
        double V[3][3] = {{1,0,0},{0,1,0},{0,0,1}};
        const int pairs[3][2] = {{0,1},{0,2},{1,2}};
        const double scale0 = fabs(G[0][0]) + fabs(G[1][1]) + fabs(G[2][2]) + 1e-300;
        for (int sweep = 0; sweep < 6; ++sweep) {
            double off = fabs(G[0][1]) + fabs(G[0][2]) + fabs(G[1][2]);
            if (off < 1e-28 * scale0) break;
            for (int pi_i = 0; pi_i < 3; ++pi_i) {
                int p = pairs[pi_i][0], q = pairs[pi_i][1];
                double apq = G[p][q];
                if (fabs(apq) < 1e-30 * scale0) continue;
                double tau = (G[q][q] - G[p][p]) * drcp(2.0 * apq);
                double tt = ((tau >= 0) ? 1.0 : -1.0) * drcp(fabs(tau) + sqrt(1.0 + tau * tau));
                double c = drcp(sqrt(1.0 + tt * tt));
                double s = tt * c;
                double gpp = G[p][p], gqq = G[q][q];
                G[p][p] = gpp - tt * apq;
                G[q][q] = gqq + tt * apq;
                G[p][q] = G[q][p] = 0.0;
                int r = 3 - p - q;
                double grp = G[r][p], grq = G[r][q];
                G[r][p] = G[p][r] = c * grp - s * grq;
                G[r][q] = G[q][r] = s * grp + c * grq;
                for (int rr = 0; rr < 3; ++rr) {
                    double vrp = V[rr][p], vrq = V[rr][q];
                    V[rr][p] = c * vrp - s * vrq;
                    V[rr][q] = s * vrp + c * vrq;
                }
            }
        }

        // M = V diag(1/sqrt(lam)) V^T ; R0 = A*M (polar factor = U@Vh)
        double invs[3];
        for (int i = 0; i < 3; ++i) {
            double lam = G[i][i];
            invs[i] = drcp(sqrt(lam > 1e-300 ? lam : 1e-300));
        }
        double M[3][3];
        for (int i = 0; i < 3; ++i)
            for (int j = 0; j < 3; ++j) {
                double acc = 0;
                for (int m2 = 0; m2 < 3; ++m2) acc += V[i][m2] * V[j][m2] * invs[m2];
                M[i][j] = acc;
            }
        double R0[3][3];
        for (int d = 0; d < 3; ++d)
            for (int e = 0; e < 3; ++e) {
                double acc = 0;
                for (int m2 = 0; m2 < 3; ++m2) acc += A[d][m2] * M[m2][e];
                R0[d][e] = acc;
            }

        // reference det-flip == flip 3rd column of R0
        double det = R0[0][0] * (R0[1][1] * R0[2][2] - R0[1][2] * R0[2][1])
                   - R0[0][1] * (R0[1][0] * R0[2][2] - R0[1][2] * R0[2][0])
                   + R0[0][2] * (R0[1][0] * R0[2][1] - R0[1][1] * R0[2][0]);
        double sg = (det >= 0.0) ? 1.0 : -1.0;
        R0[0][2] *= sg; R0[1][2] *= sg; R0[2][2] *= sg;

        double T[3];
        for (int d = 0; d < 3; ++d)
            T[d] = cy[d] - (R0[d][0] * cx[0] + R0[d][1] * cx[1] + R0[d][2] * cx[2]);

        if (sub == 0) {
            rt_s[bb][0] = (float)R0[0][0]; rt_s[bb][1] = (float)R0[0][1]; rt_s[bb][2] = (float)R0[0][2];
            rt_s[bb][3] = (float)R0[1][0]; rt_s[bb][4] = (float)R0[1][1]; rt_s[bb][5] = (float)R0[1][2];
            rt_s[bb][6] = (float)R0[2][0]; rt_s[bb][7] = (float)R0[2][1]; rt_s[bb][8] = (float)R0[2][2];
            rt_s[bb][9] = (float)T[0]; rt_s[bb][10] = (float)T[1]; rt_s[bb][11] = (float)T[2];
        }
    }
    __syncthreads();

    // ---- phase 2: apply (loads already in registers), vectorized stores ----
    const float* rt = rt_s[b];
    float y0[4], y1[4], y2[4];
#pragma unroll
    for (int i = 0; i < 4; ++i) {
        float x0 = xa[i], x1 = xb[i], x2 = xc[i];
        y0[i] = fmaf(rt[0], x0, fmaf(rt[1], x1, fmaf(rt[2], x2, rt[9])));
        y1[i] = fmaf(rt[3], x0, fmaf(rt[4], x1, fmaf(rt[5], x2, rt[10])));
        y2[i] = fmaf(rt[6], x0, fmaf(rt[7], x1, fmaf(rt[8], x2, rt[11])));
    }
    f32x4 o0 = {y0[0], y1[0], y2[0], y0[1]};
    f32x4 o1 = {y1[1], y2[1], y0[2], y1[2]};
    f32x4 o2 = {y2[2], y0[3], y1[3], y2[3]};
    f32x4* op = (f32x4*)(out + (size_t)idx0 * 3);   // 48-B aligned (idx0 % 4 == 0)
    op[0] = o0;
    op[1] = o1;
    op[2] = o2;
}

extern "C" void kernel_launch(void* const* d_in, const int* in_sizes, int n_in,
                              void* d_out, int out_size, void* d_ws, size_t ws_size,
                              hipStream_t stream) {
    const float* tmpl = (const float*)d_in[0];   // (B,3,N) f32
    const float* srcf = (const float*)d_in[1];   // (B,3,N) f32
    const float* Wmat = (const float*)d_in[2];   // (3,K) f32
    float* out = (float*)d_out;                  // (B,N,3) f32

    // workspace (floats): [0, 262144) partials | [262144, +1024) Zs | [+1024, +3072) Ss
    float* part = (float*)d_ws;
    float* Zs   = (float*)d_ws + 262144;
    float* Ss   = (float*)d_ws + 262144 + 1024;

    // no memset: every ws location read is written first (no atomics anywhere)
    k_sum<<<1024, 256, 0, stream>>>(tmpl, srcf, Wmat, part);
    k_reduce<<<16, 256, 0, stream>>>(part, Zs, Ss);
    k_apply<<<512, 256, 0, stream>>>(srcf, Zs, Ss, out);
}